// Round 18
// baseline (1818.032 us; speedup 1.0000x reference)
//
#include <hip/hip_runtime.h>
#include <hip/hip_bf16.h>
#include <math.h>
#include <type_traits>

#define HIDDEN 256
#define SEQ 2048
#define BATCH 64
#define INSZ 128
#define OUTSZ 64
#define DTC 0.05f
#define CCH 32           // pipeline chunks
#define CHS (SEQ / CCH)  // 64 steps per chunk

typedef _Float16 f16x8 __attribute__((ext_vector_type(8)));
typedef float f32x4 __attribute__((ext_vector_type(4)));

// ---------------- K0: complexity net + alphas + zero h_carry slots ----------------
__global__ __launch_bounds__(1024) void prep_kernel(
    const float* __restrict__ x, const float* __restrict__ cw1, const float* __restrict__ cb1,
    const float* __restrict__ cw2, const float* __restrict__ cb2,
    const float* __restrict__ tau_b, const float* __restrict__ tmw, const float* __restrict__ tmb,
    float* __restrict__ alphas, float* __restrict__ h_carry)   // [3][64], [3][64][256]
{
    __shared__ float p_lds[8][128];
    __shared__ float xm[128];
    __shared__ float t1[64];
    int b = blockIdx.x;
    int tid = threadIdx.x;
    if (tid < 256) {
        h_carry[0 * 16384 + b * 256 + tid] = 0.f;
        h_carry[1 * 16384 + b * 256 + tid] = 0.f;
        h_carry[2 * 16384 + b * 256 + tid] = 0.f;
    }
    int c = tid & 127, sh = tid >> 7;
    const float* xb = x + (size_t)b * SEQ * INSZ;
    float s = 0.f;
    for (int t = sh * 256; t < (sh + 1) * 256; ++t) s += xb[(size_t)t * INSZ + c];
    p_lds[sh][c] = s;
    __syncthreads();
    if (tid < 128) {
        float m = 0.f;
        #pragma unroll
        for (int i = 0; i < 8; ++i) m += p_lds[i][tid];
        xm[tid] = m / (float)SEQ;
    }
    __syncthreads();
    if (tid < 64) {
        float acc = cb1[tid];
        for (int k = 0; k < 128; ++k) acc += xm[k] * cw1[tid * 128 + k];
        t1[tid] = fmaxf(acc, 0.f);
    }
    __syncthreads();
    if (tid == 0) {
        float acc = cb2[0];
        for (int k = 0; k < 64; ++k) acc += t1[k] * cw2[k];
        float comp = 1.f / (1.f + expf(-acc));
        for (int i = 0; i < 3; ++i) {
            float lg[4], mx = -1e30f;
            for (int j = 0; j < 4; ++j) { lg[j] = comp * tmw[i * 4 + j] + tmb[i * 4 + j]; mx = fmaxf(mx, lg[j]); }
            float den = 0.f;
            for (int j = 0; j < 4; ++j) { lg[j] = expf(lg[j] - mx); den += lg[j]; }
            float mt = 0.f;
            for (int j = 0; j < 4; ++j) mt += tau_b[i * 4 + j] * (lg[j] / den);
            alphas[i * 64 + b] = expf(-DTC / mt);
        }
    }
}

// ---------------- Wf = W_in0 @ pw  (256x128), bf = W_in0 @ pb + bias0 ----------------
__global__ __launch_bounds__(128) void wf_kernel(
    const float* __restrict__ W_in0, const float* __restrict__ pw,
    const float* __restrict__ pb, const float* __restrict__ bias0,
    float* __restrict__ Wf, float* __restrict__ bf)
{
    __shared__ float wrow[256];
    int j = blockIdx.x, k = threadIdx.x;
    for (int m = k; m < 256; m += 128) wrow[m] = W_in0[j * 256 + m];
    __syncthreads();
    float s = 0.f;
    for (int m = 0; m < 256; ++m) s = fmaf(wrow[m], pw[m * 128 + k], s);
    Wf[j * 128 + k] = s;
    if (k == 0) {
        float sb = bias0[j];
        for (int m = 0; m < 256; ++m) sb = fmaf(wrow[m], pb[m], sb);
        bf[j] = sb;
    }
}

__device__ __forceinline__ unsigned pkrtz(float a, float b) {
    return __builtin_bit_cast(unsigned, __builtin_amdgcn_cvt_pkrtz(a, b));
}

__device__ __forceinline__ float fast_tanh(float x) {
    float ex = __expf(2.f * x);
    float r = __builtin_amdgcn_rcpf(ex + 1.f);
    return 1.f - 2.f * r;
}

// LDS-only barrier: waits ds ops but leaves global loads/stores in flight.
__device__ __forceinline__ void barrier_lds_only() {
    asm volatile("s_waitcnt lgkmcnt(0)\n\ts_barrier" ::: "memory");
}

// ---------------- MFMA GEMM for ext0 (full seq) — now with LDS-staged coalesced C store ----------------
__global__ __launch_bounds__(256, 2) void gemm0_kernel(
    const float* __restrict__ Asrc,  // x: f32 [M][128]
    const float* __restrict__ W,     // Wf [256][128] f32
    const float* __restrict__ bias,  // bf [256]
    float* __restrict__ C)           // buf [M][256] f32
{
    constexpr int KD = 128, KT = 4, ROWB = 256;
    __shared__ alignas(16) char alds[32 * ROWB];   // 8 KB
    __shared__ alignas(16) float ctile[32 * 256];  // 32 KB
    const int tid = threadIdx.x;
    const int wave = tid >> 6, lane = tid & 63;
    const int bl = lane & 15, q = lane >> 4;
    const int m0 = blockIdx.x * 32;

    f16x8 bfrag[4][KT];
    float bv[4];
    #pragma unroll
    for (int nt = 0; nt < 4; ++nt) {
        int n = wave * 64 + nt * 16 + bl;
        const float* wr = W + (size_t)n * KD;
        #pragma unroll
        for (int kt = 0; kt < KT; ++kt) {
            const float4* wp = (const float4*)(wr + kt * 32 + q * 8);
            float4 u0 = wp[0], u1 = wp[1];
            uint4 u = { pkrtz(u0.x, u0.y), pkrtz(u0.z, u0.w),
                        pkrtz(u1.x, u1.y), pkrtz(u1.z, u1.w) };
            bfrag[nt][kt] = __builtin_bit_cast(f16x8, u);
        }
        bv[nt] = bias[n];
    }
    #pragma unroll
    for (int it = 0; it < 2; ++it) {
        int idx = tid + it * 256;
        int row = idx >> 4, chunk = idx & 15;
        const float4* sp = (const float4*)(Asrc + (size_t)(m0 + row) * KD + chunk * 8);
        float4 f0 = sp[0], f1 = sp[1];
        uint4 u = { pkrtz(f0.x, f0.y), pkrtz(f0.z, f0.w),
                    pkrtz(f1.x, f1.y), pkrtz(f1.z, f1.w) };
        *(uint4*)(alds + row * ROWB + ((chunk * 16) ^ ((row & 7) << 4))) = u;
    }
    __syncthreads();

    f32x4 acc[2][4];
    #pragma unroll
    for (int mt = 0; mt < 2; ++mt)
        #pragma unroll
        for (int nt = 0; nt < 4; ++nt) acc[mt][nt] = (f32x4){0.f, 0.f, 0.f, 0.f};
    #pragma unroll
    for (int kt = 0; kt < KT; ++kt) {
        int inner = kt * 64 + q * 16;
        f16x8 a0 = __builtin_bit_cast(f16x8,
            *(const uint4*)(alds + (0 * 16 + bl) * ROWB + (inner ^ ((bl & 7) << 4))));
        f16x8 a1 = __builtin_bit_cast(f16x8,
            *(const uint4*)(alds + (1 * 16 + bl) * ROWB + (inner ^ ((bl & 7) << 4))));
        #pragma unroll
        for (int nt = 0; nt < 4; ++nt) {
            acc[0][nt] = __builtin_amdgcn_mfma_f32_16x16x32_f16(a0, bfrag[nt][kt], acc[0][nt], 0, 0, 0);
            acc[1][nt] = __builtin_amdgcn_mfma_f32_16x16x32_f16(a1, bfrag[nt][kt], acc[1][nt], 0, 0, 0);
        }
    }
    // scatter D into ctile (LDS), then write coalesced 1KB rows
    #pragma unroll
    for (int mt = 0; mt < 2; ++mt)
        #pragma unroll
        for (int nt = 0; nt < 4; ++nt) {
            int col = wave * 64 + nt * 16 + bl;
            #pragma unroll
            for (int r = 0; r < 4; ++r)
                ctile[(mt * 16 + q * 4 + r) * 256 + col] = acc[mt][nt][r] + bv[nt];
        }
    __syncthreads();
    #pragma unroll
    for (int it = 0; it < 8; ++it) {
        int idx = tid + it * 256;
        int row = idx >> 6, seg = idx & 63;
        *(uint4*)(C + (size_t)(m0 + row) * 256 + seg * 4) = *(const uint4*)(ctile + row * 256 + seg * 4);
    }
}

// ---------------- scan chunk: MFMA matvec, split accumulation chains (4+4 deep) ----------------
__device__ __forceinline__ void scan_chunk(
    char* smem, float* buf, const float* __restrict__ W_rec,
    const float* __restrict__ alphas, float* __restrict__ h_carry,
    int b, int c, int write_all)
{
    _Float16 (*hlds)[256] = (_Float16 (*)[256])smem;   // [2][256]
    const int tid = threadIdx.x;
    const int wave = tid >> 6, lane = tid & 63;
    const int bl = lane & 15, q = lane >> 4;
    const int mt_own = bl >> 2, r_own = bl & 3;
    const int m = wave * 64 + mt_own * 16 + q * 4 + r_own;

    f16x8 afrag[4][8];
    #pragma unroll
    for (int mt = 0; mt < 4; ++mt) {
        const float* wr = W_rec + (size_t)(wave * 64 + mt * 16 + bl) * 256;
        #pragma unroll
        for (int kt = 0; kt < 8; ++kt) {
            const float4* wp = (const float4*)(wr + kt * 32 + q * 8);
            float4 wa = wp[0], wb4 = wp[1];
            uint4 u = { pkrtz(wa.x, wa.y), pkrtz(wa.z, wa.w),
                        pkrtz(wb4.x, wb4.y), pkrtz(wb4.z, wb4.w) };
            afrag[mt][kt] = __builtin_bit_cast(f16x8, u);
        }
    }

    const float alpha = alphas[b], onema = 1.f - alpha;
    float* bb = buf + (size_t)b * SEQ * HIDDEN;
    const int t0 = c * CHS, tend = t0 + CHS;

    float h_reg = h_carry[b * 256 + m];    // true carry, or speculative 0 at chunk 0
    hlds[0][m] = (_Float16)h_reg;
    float e_cur = bb[(size_t)t0 * HIDDEN + m];
    float e_n1  = bb[(size_t)(t0 + 1) * HIDDEN + m];
    __syncthreads();

    auto step = [&](auto CB, int t) {
        constexpr int CUR = decltype(CB)::value;
        const char* rb = (const char*)&hlds[CUR][0];
        uint4 bq0 = *(const uint4*)(rb + q * 16);
        uint4 bq1 = *(const uint4*)(rb + 64 + q * 16);
        uint4 bq2 = *(const uint4*)(rb + 128 + q * 16);
        uint4 bq3 = *(const uint4*)(rb + 192 + q * 16);
        uint4 bq4 = *(const uint4*)(rb + 256 + q * 16);
        uint4 bq5 = *(const uint4*)(rb + 320 + q * 16);
        uint4 bq6 = *(const uint4*)(rb + 384 + q * 16);
        uint4 bq7 = *(const uint4*)(rb + 448 + q * 16);
        float e_n2 = 0.f;
        if (t + 2 < tend) e_n2 = bb[(size_t)(t + 2) * HIDDEN + m];

        // two independent 4-deep accumulation chains per m-tile (halves MFMA dep latency)
        f32x4 ya0 = {0.f,0.f,0.f,0.f}, ya1 = {0.f,0.f,0.f,0.f};
        f32x4 ya2 = {0.f,0.f,0.f,0.f}, ya3 = {0.f,0.f,0.f,0.f};
        f32x4 yb0 = {0.f,0.f,0.f,0.f}, yb1 = {0.f,0.f,0.f,0.f};
        f32x4 yb2 = {0.f,0.f,0.f,0.f}, yb3 = {0.f,0.f,0.f,0.f};
        #define MSTEPA(BQ, KT) { f16x8 bf = __builtin_bit_cast(f16x8, BQ);                   \
            ya0 = __builtin_amdgcn_mfma_f32_16x16x32_f16(afrag[0][KT], bf, ya0, 0, 0, 0);    \
            ya1 = __builtin_amdgcn_mfma_f32_16x16x32_f16(afrag[1][KT], bf, ya1, 0, 0, 0);    \
            ya2 = __builtin_amdgcn_mfma_f32_16x16x32_f16(afrag[2][KT], bf, ya2, 0, 0, 0);    \
            ya3 = __builtin_amdgcn_mfma_f32_16x16x32_f16(afrag[3][KT], bf, ya3, 0, 0, 0); }
        #define MSTEPB(BQ, KT) { f16x8 bf = __builtin_bit_cast(f16x8, BQ);                   \
            yb0 = __builtin_amdgcn_mfma_f32_16x16x32_f16(afrag[0][KT], bf, yb0, 0, 0, 0);    \
            yb1 = __builtin_amdgcn_mfma_f32_16x16x32_f16(afrag[1][KT], bf, yb1, 0, 0, 0);    \
            yb2 = __builtin_amdgcn_mfma_f32_16x16x32_f16(afrag[2][KT], bf, yb2, 0, 0, 0);    \
            yb3 = __builtin_amdgcn_mfma_f32_16x16x32_f16(afrag[3][KT], bf, yb3, 0, 0, 0); }
        MSTEPA(bq0, 0) MSTEPB(bq4, 4) MSTEPA(bq1, 1) MSTEPB(bq5, 5)
        MSTEPA(bq2, 2) MSTEPB(bq6, 6) MSTEPA(bq3, 3) MSTEPB(bq7, 7)
        #undef MSTEPA
        #undef MSTEPB

        f32x4 am = (mt_own == 0) ? ya0 : (mt_own == 1) ? ya1 : (mt_own == 2) ? ya2 : ya3;
        f32x4 bm = (mt_own == 0) ? yb0 : (mt_own == 1) ? yb1 : (mt_own == 2) ? yb2 : yb3;
        float sa = (r_own == 0) ? am[0] : (r_own == 1) ? am[1] : (r_own == 2) ? am[2] : am[3];
        float sb = (r_own == 0) ? bm[0] : (r_own == 1) ? bm[1] : (r_own == 2) ? bm[2] : bm[3];

        float act = fast_tanh(sa + sb + e_cur);
        h_reg = alpha * h_reg + onema * act;
        hlds[CUR ^ 1][m] = (_Float16)h_reg;
        if (write_all)
            *((_Float16*)(bb + (size_t)t * HIDDEN) + m) = (_Float16)h_reg;
        barrier_lds_only();
        e_cur = e_n1;
        e_n1 = e_n2;
    };

    for (int t = t0; t < tend; t += 2) {
        step(std::integral_constant<int, 0>{}, t);
        step(std::integral_constant<int, 1>{}, t + 1);
    }
    h_carry[b * 256 + m] = h_reg;
}

// ---------------- ext GEMM chunk: one 64-row block per (batch, chunk); KD=256, f16 A in-place ----------------
__device__ __forceinline__ void gemm_chunk(
    char* smem, float* buf, const float* __restrict__ W,
    const float* __restrict__ bias, int g, int c)
{
    constexpr int KD = 256, KT = 8, ROWB = 512;
    char* alds = smem;   // 64 rows * 512B = 32 KB
    const int tid = threadIdx.x;
    const int wave = tid >> 6, lane = tid & 63;
    const int bl = lane & 15, q = lane >> 4;
    const size_t m0 = (size_t)g * SEQ + (size_t)c * CHS;

    f16x8 bfrag[4][KT];
    float bv[4];
    #pragma unroll
    for (int nt = 0; nt < 4; ++nt) {
        int n = wave * 64 + nt * 16 + bl;
        const float* wr = W + (size_t)n * KD;
        #pragma unroll
        for (int kt = 0; kt < KT; ++kt) {
            const float4* wp = (const float4*)(wr + kt * 32 + q * 8);
            float4 u0 = wp[0], u1 = wp[1];
            uint4 u = { pkrtz(u0.x, u0.y), pkrtz(u0.z, u0.w),
                        pkrtz(u1.x, u1.y), pkrtz(u1.z, u1.w) };
            bfrag[nt][kt] = __builtin_bit_cast(f16x8, u);
        }
        bv[nt] = bias[n];
    }
    // stage 64 f16 rows (exactly; r17's loop over-ran its 32-row tile)
    #pragma unroll
    for (int it = 0; it < 8; ++it) {
        int idx = tid + it * 256;
        int row = idx >> 5, chunk = idx & 31;
        uint4 u = *(const uint4*)((const char*)buf + (m0 + row) * 1024 + chunk * 16);
        *(uint4*)(alds + row * ROWB + ((chunk * 16) ^ ((row & 7) << 4))) = u;
    }
    __syncthreads();

    f32x4 acc[4][4];
    #pragma unroll
    for (int mt = 0; mt < 4; ++mt)
        #pragma unroll
        for (int nt = 0; nt < 4; ++nt) acc[mt][nt] = (f32x4){0.f, 0.f, 0.f, 0.f};
    #pragma unroll
    for (int kt = 0; kt < KT; ++kt) {
        int inner = kt * 64 + q * 16;
        #pragma unroll
        for (int mt = 0; mt < 4; ++mt) {
            f16x8 a = __builtin_bit_cast(f16x8,
                *(const uint4*)(alds + (mt * 16 + bl) * ROWB + (inner ^ ((bl & 7) << 4))));
            #pragma unroll
            for (int nt = 0; nt < 4; ++nt)
                acc[mt][nt] = __builtin_amdgcn_mfma_f32_16x16x32_f16(a, bfrag[nt][kt], acc[mt][nt], 0, 0, 0);
        }
    }
    #pragma unroll
    for (int mt = 0; mt < 4; ++mt)
        #pragma unroll
        for (int nt = 0; nt < 4; ++nt) {
            int col = wave * 64 + nt * 16 + bl;
            #pragma unroll
            for (int r = 0; r < 4; ++r)
                buf[(m0 + mt * 16 + q * 4 + r) * 256 + col] = acc[mt][nt][r] + bv[nt];
        }
}

// ---------------- stage megakernel ----------------
// blocks [0,64): scanL0(stage); [64,128): scanL1(stage-2); [128,192): scanL2(stage-4);
// [192,256): gemm1(stage-1); [256,320): gemm2(stage-3). Deps ride launch order.
__global__ __launch_bounds__(256, 1) void stage_kernel(
    int stage, float* buf,
    const float* __restrict__ W_rec, const float* __restrict__ W_in,
    const float* __restrict__ bias,  const float* __restrict__ alphas,
    float* __restrict__ h_carry)
{
    __shared__ alignas(16) char smem[32768];
    int blk = blockIdx.x;
    if (blk < 192) {
        int layer = blk >> 6;
        int c = stage - 2 * layer;
        if (c < 0 || c >= CCH) return;
        scan_chunk(smem, buf, W_rec + (size_t)layer * 65536, alphas + layer * 64,
                   h_carry + (size_t)layer * 16384, blk & 63, c, layer < 2);
    } else {
        int g = blk - 192;
        int which = g >> 6;          // 0: ext1 gemm, 1: ext2 gemm
        int gl = g & 63;
        int c = stage - 1 - 2 * which;
        if (c < 0 || c >= CCH) return;
        int lw = which + 1;
        gemm_chunk(smem, buf, W_in + (size_t)lw * 65536, bias + lw * 256, gl, c);
    }
}

// ---------------- final projection from h_carry[2] ----------------
__global__ __launch_bounds__(256) void outproj_kernel(
    const float* __restrict__ h_carry, const float* __restrict__ ow, const float* __restrict__ ob,
    float* __restrict__ out)
{
    __shared__ float h_l[256];
    __shared__ float p_lds[4][64];
    int b = blockIdx.x;
    int tid = threadIdx.x;
    h_l[tid] = h_carry[b * 256 + tid];
    __syncthreads();
    int o = tid & 63, qq = tid >> 6;
    float s = 0.f;
    const float4* wp = (const float4*)(ow + o * 256 + qq * 64);
    const float4* hp = (const float4*)(h_l + qq * 64);
    #pragma unroll
    for (int m = 0; m < 16; ++m) {
        float4 wv = wp[m]; float4 hv = hp[m];
        s = fmaf(wv.x, hv.x, s); s = fmaf(wv.y, hv.y, s);
        s = fmaf(wv.z, hv.z, s); s = fmaf(wv.w, hv.w, s);
    }
    p_lds[qq][o] = s;
    __syncthreads();
    if (tid < 64)
        out[b * 64 + tid] = p_lds[0][tid] + p_lds[1][tid] + p_lds[2][tid] + p_lds[3][tid] + ob[tid];
}

extern "C" void kernel_launch(void* const* d_in, const int* in_sizes, int n_in,
                              void* d_out, int out_size, void* d_ws, size_t ws_size,
                              hipStream_t stream)
{
    const float* x     = (const float*)d_in[0];
    const float* cw1   = (const float*)d_in[1];
    const float* cb1   = (const float*)d_in[2];
    const float* cw2   = (const float*)d_in[3];
    const float* cb2   = (const float*)d_in[4];
    const float* pw    = (const float*)d_in[5];
    const float* pb    = (const float*)d_in[6];
    const float* W_rec = (const float*)d_in[7];
    const float* W_in  = (const float*)d_in[8];
    const float* bias  = (const float*)d_in[9];
    const float* tau_b = (const float*)d_in[10];
    const float* tmw   = (const float*)d_in[11];
    const float* tmb   = (const float*)d_in[12];
    const float* ow    = (const float*)d_in[13];
    const float* ob    = (const float*)d_in[14];
    float* out = (float*)d_out;

    char* ws = (char*)d_ws;
    float* alphas  = (float*)ws;                       // 192 f
    float* h_carry = (float*)(ws + 4096);              // [3][64][256] f = 192KB
    float* bf      = (float*)(ws + 262144);            // 256 f
    float* Wf      = (float*)(ws + 266240);            // 256*128 f
    float* buf     = (float*)(ws + 1048576);           // [64][2048][256] f32 = 134.2MB

    const int MROWS = BATCH * SEQ;      // 131072
    const int NGBLK = 192 + 128;        // 320 blocks per stage

    prep_kernel<<<64, 1024, 0, stream>>>(x, cw1, cb1, cw2, cb2, tau_b, tmw, tmb, alphas, h_carry);
    wf_kernel<<<256, 128, 0, stream>>>(W_in, pw, pb, bias, Wf, bf);

    // ext0 = x @ Wf.T + bf (input projection + W_in0 fused), full sequence
    gemm0_kernel<<<MROWS / 32, 256, 0, stream>>>(x, Wf, bf, buf);

    // speculative chunked pipeline: 3 scans + 2 ext-gemms overlapped across launches
    for (int s = 0; s < CCH + 4; ++s)
        stage_kernel<<<NGBLK, 256, 0, stream>>>(s, buf, W_rec, W_in, bias, alphas, h_carry);

    outproj_kernel<<<64, 256, 0, stream>>>(h_carry + 2 * 16384, ow, ob, out);
}

// Round 19
// 1494.418 us; speedup vs baseline: 1.2165x; 1.2165x over previous
//
#include <hip/hip_runtime.h>
#include <hip/hip_bf16.h>
#include <math.h>
#include <type_traits>

#define HIDDEN 256
#define SEQ 2048
#define BATCH 64
#define INSZ 128
#define OUTSZ 64
#define DTC 0.05f
#define CCH 32           // pipeline chunks
#define CHS (SEQ / CCH)  // 64 steps per chunk
#define TBLK (CHS / 32)  // 2 gemm row-blocks per batch-chunk

typedef _Float16 f16x8 __attribute__((ext_vector_type(8)));
typedef float f32x4 __attribute__((ext_vector_type(4)));

// ---------------- K0: complexity net + alphas + zero h_carry slots ----------------
__global__ __launch_bounds__(1024) void prep_kernel(
    const float* __restrict__ x, const float* __restrict__ cw1, const float* __restrict__ cb1,
    const float* __restrict__ cw2, const float* __restrict__ cb2,
    const float* __restrict__ tau_b, const float* __restrict__ tmw, const float* __restrict__ tmb,
    float* __restrict__ alphas, float* __restrict__ h_carry)   // [3][64], [3][64][256]
{
    __shared__ float p_lds[8][128];
    __shared__ float xm[128];
    __shared__ float t1[64];
    int b = blockIdx.x;
    int tid = threadIdx.x;
    if (tid < 256) {
        h_carry[0 * 16384 + b * 256 + tid] = 0.f;
        h_carry[1 * 16384 + b * 256 + tid] = 0.f;
        h_carry[2 * 16384 + b * 256 + tid] = 0.f;
    }
    int c = tid & 127, sh = tid >> 7;
    const float* xb = x + (size_t)b * SEQ * INSZ;
    float s = 0.f;
    for (int t = sh * 256; t < (sh + 1) * 256; ++t) s += xb[(size_t)t * INSZ + c];
    p_lds[sh][c] = s;
    __syncthreads();
    if (tid < 128) {
        float m = 0.f;
        #pragma unroll
        for (int i = 0; i < 8; ++i) m += p_lds[i][tid];
        xm[tid] = m / (float)SEQ;
    }
    __syncthreads();
    if (tid < 64) {
        float acc = cb1[tid];
        for (int k = 0; k < 128; ++k) acc += xm[k] * cw1[tid * 128 + k];
        t1[tid] = fmaxf(acc, 0.f);
    }
    __syncthreads();
    if (tid == 0) {
        float acc = cb2[0];
        for (int k = 0; k < 64; ++k) acc += t1[k] * cw2[k];
        float comp = 1.f / (1.f + expf(-acc));
        for (int i = 0; i < 3; ++i) {
            float lg[4], mx = -1e30f;
            for (int j = 0; j < 4; ++j) { lg[j] = comp * tmw[i * 4 + j] + tmb[i * 4 + j]; mx = fmaxf(mx, lg[j]); }
            float den = 0.f;
            for (int j = 0; j < 4; ++j) { lg[j] = expf(lg[j] - mx); den += lg[j]; }
            float mt = 0.f;
            for (int j = 0; j < 4; ++j) mt += tau_b[i * 4 + j] * (lg[j] / den);
            alphas[i * 64 + b] = expf(-DTC / mt);
        }
    }
}

// ---------------- Wf = W_in0 @ pw  (256x128), bf = W_in0 @ pb + bias0 ----------------
__global__ __launch_bounds__(128) void wf_kernel(
    const float* __restrict__ W_in0, const float* __restrict__ pw,
    const float* __restrict__ pb, const float* __restrict__ bias0,
    float* __restrict__ Wf, float* __restrict__ bf)
{
    __shared__ float wrow[256];
    int j = blockIdx.x, k = threadIdx.x;
    for (int m = k; m < 256; m += 128) wrow[m] = W_in0[j * 256 + m];
    __syncthreads();
    float s = 0.f;
    for (int m = 0; m < 256; ++m) s = fmaf(wrow[m], pw[m * 128 + k], s);
    Wf[j * 128 + k] = s;
    if (k == 0) {
        float sb = bias0[j];
        for (int m = 0; m < 256; ++m) sb = fmaf(wrow[m], pb[m], sb);
        bf[j] = sb;
    }
}

__device__ __forceinline__ unsigned pkrtz(float a, float b) {
    return __builtin_bit_cast(unsigned, __builtin_amdgcn_cvt_pkrtz(a, b));
}

// ---------------- pack a 256x256 f32 matrix into per-lane f16 fragments ----------------
// P[(wave*4+mt)*8+kt][lane] (16B each): row = wave*64+mt*16+(lane&15), k = kt*32+(lane>>4)*8
__global__ __launch_bounds__(64) void wpack_kernel(
    const float* __restrict__ W, _Float16* __restrict__ P)
{
    int blk = blockIdx.x;            // (wave*4+mt)*8+kt, 128 blocks
    int wave = blk >> 5, mt = (blk >> 3) & 3, kt = blk & 7;
    int lane = threadIdx.x;
    int row = wave * 64 + mt * 16 + (lane & 15);
    int kcol = kt * 32 + (lane >> 4) * 8;
    const float4* s = (const float4*)(W + (size_t)row * 256 + kcol);
    float4 a = s[0], b = s[1];
    uint4 u = { pkrtz(a.x, a.y), pkrtz(a.z, a.w), pkrtz(b.x, b.y), pkrtz(b.z, b.w) };
    *(uint4*)((char*)P + (size_t)blk * 1024 + lane * 16) = u;
}

__device__ __forceinline__ float fast_tanh(float x) {
    float ex = __expf(2.f * x);
    float r = __builtin_amdgcn_rcpf(ex + 1.f);
    return 1.f - 2.f * r;
}

// LDS-only barrier: waits ds ops but leaves global loads/stores in flight.
__device__ __forceinline__ void barrier_lds_only() {
    asm volatile("s_waitcnt lgkmcnt(0)\n\ts_barrier" ::: "memory");
}

// ---------------- MFMA GEMM for ext0 (full seq; r17-verified) ----------------
__global__ __launch_bounds__(256, 2) void gemm0_kernel(
    const float* __restrict__ Asrc,  // x: f32 [M][128]
    const float* __restrict__ W,     // Wf [256][128] f32
    const float* __restrict__ bias,  // bf [256]
    float* __restrict__ C)           // buf [M][256] f32
{
    constexpr int KD = 128, KT = 4, ROWB = 256;
    __shared__ alignas(16) char alds[32 * ROWB];
    const int tid = threadIdx.x;
    const int wave = tid >> 6, lane = tid & 63;
    const int bl = lane & 15, q = lane >> 4;
    const int m0 = blockIdx.x * 32;

    f16x8 bfrag[4][KT];
    float bv[4];
    #pragma unroll
    for (int nt = 0; nt < 4; ++nt) {
        int n = wave * 64 + nt * 16 + bl;
        const float* wr = W + (size_t)n * KD;
        #pragma unroll
        for (int kt = 0; kt < KT; ++kt) {
            const float4* wp = (const float4*)(wr + kt * 32 + q * 8);
            float4 u0 = wp[0], u1 = wp[1];
            uint4 u = { pkrtz(u0.x, u0.y), pkrtz(u0.z, u0.w),
                        pkrtz(u1.x, u1.y), pkrtz(u1.z, u1.w) };
            bfrag[nt][kt] = __builtin_bit_cast(f16x8, u);
        }
        bv[nt] = bias[n];
    }
    #pragma unroll
    for (int it = 0; it < 2; ++it) {
        int idx = tid + it * 256;
        int row = idx >> 4, chunk = idx & 15;
        const float4* sp = (const float4*)(Asrc + (size_t)(m0 + row) * KD + chunk * 8);
        float4 f0 = sp[0], f1 = sp[1];
        uint4 u = { pkrtz(f0.x, f0.y), pkrtz(f0.z, f0.w),
                    pkrtz(f1.x, f1.y), pkrtz(f1.z, f1.w) };
        *(uint4*)(alds + row * ROWB + ((chunk * 16) ^ ((row & 7) << 4))) = u;
    }
    __syncthreads();

    f32x4 acc[2][4];
    #pragma unroll
    for (int mt = 0; mt < 2; ++mt)
        #pragma unroll
        for (int nt = 0; nt < 4; ++nt) acc[mt][nt] = (f32x4){0.f, 0.f, 0.f, 0.f};
    #pragma unroll
    for (int kt = 0; kt < KT; ++kt) {
        int inner = kt * 64 + q * 16;
        f16x8 a0 = __builtin_bit_cast(f16x8,
            *(const uint4*)(alds + (0 * 16 + bl) * ROWB + (inner ^ ((bl & 7) << 4))));
        f16x8 a1 = __builtin_bit_cast(f16x8,
            *(const uint4*)(alds + (1 * 16 + bl) * ROWB + (inner ^ ((bl & 7) << 4))));
        #pragma unroll
        for (int nt = 0; nt < 4; ++nt) {
            acc[0][nt] = __builtin_amdgcn_mfma_f32_16x16x32_f16(a0, bfrag[nt][kt], acc[0][nt], 0, 0, 0);
            acc[1][nt] = __builtin_amdgcn_mfma_f32_16x16x32_f16(a1, bfrag[nt][kt], acc[1][nt], 0, 0, 0);
        }
    }
    #pragma unroll
    for (int mt = 0; mt < 2; ++mt)
        #pragma unroll
        for (int nt = 0; nt < 4; ++nt) {
            int col = wave * 64 + nt * 16 + bl;
            #pragma unroll
            for (int r = 0; r < 4; ++r)
                C[(size_t)(m0 + mt * 16 + q * 4 + r) * 256 + col] = acc[mt][nt][r] + bv[nt];
        }
}

// ---------------- scan chunk (r17 body; afrag from packed f16 fragments) ----------------
__device__ __forceinline__ void scan_chunk(
    char* smem, float* buf, const _Float16* __restrict__ Wp,
    const float* __restrict__ alphas, float* __restrict__ h_carry,
    int b, int c, int write_all)
{
    _Float16 (*hlds)[256] = (_Float16 (*)[256])smem;   // [2][256]
    const int tid = threadIdx.x;
    const int wave = tid >> 6, lane = tid & 63;
    const int bl = lane & 15, q = lane >> 4;
    const int mt_own = bl >> 2, r_own = bl & 3;
    const int m = wave * 64 + mt_own * 16 + q * 4 + r_own;

    f16x8 afrag[4][8];
    #pragma unroll
    for (int mt = 0; mt < 4; ++mt)
        #pragma unroll
        for (int kt = 0; kt < 8; ++kt)
            afrag[mt][kt] = __builtin_bit_cast(f16x8,
                *(const uint4*)((const char*)Wp + (size_t)(((wave * 4 + mt) * 8 + kt) * 64 + lane) * 16));

    const float alpha = alphas[b], onema = 1.f - alpha;
    float* bb = buf + (size_t)b * SEQ * HIDDEN;
    const int t0 = c * CHS, tend = t0 + CHS;

    float h_reg = h_carry[b * 256 + m];    // true carry, or speculative 0 at chunk 0
    hlds[0][m] = (_Float16)h_reg;
    float e_cur = bb[(size_t)t0 * HIDDEN + m];
    float e_n1  = bb[(size_t)(t0 + 1) * HIDDEN + m];
    __syncthreads();

    auto step = [&](auto CB, int t) {
        constexpr int CUR = decltype(CB)::value;
        const char* rb = (const char*)&hlds[CUR][0];
        uint4 bq0 = *(const uint4*)(rb + q * 16);
        uint4 bq1 = *(const uint4*)(rb + 64 + q * 16);
        uint4 bq2 = *(const uint4*)(rb + 128 + q * 16);
        uint4 bq3 = *(const uint4*)(rb + 192 + q * 16);
        uint4 bq4 = *(const uint4*)(rb + 256 + q * 16);
        uint4 bq5 = *(const uint4*)(rb + 320 + q * 16);
        uint4 bq6 = *(const uint4*)(rb + 384 + q * 16);
        uint4 bq7 = *(const uint4*)(rb + 448 + q * 16);
        float e_n2 = 0.f;
        if (t + 2 < tend) e_n2 = bb[(size_t)(t + 2) * HIDDEN + m];

        f32x4 a0 = {0.f,0.f,0.f,0.f}, a1 = {0.f,0.f,0.f,0.f};
        f32x4 a2 = {0.f,0.f,0.f,0.f}, a3 = {0.f,0.f,0.f,0.f};
        #define MSTEP(BQ, KT) { f16x8 bf = __builtin_bit_cast(f16x8, BQ);                  \
            a0 = __builtin_amdgcn_mfma_f32_16x16x32_f16(afrag[0][KT], bf, a0, 0, 0, 0);    \
            a1 = __builtin_amdgcn_mfma_f32_16x16x32_f16(afrag[1][KT], bf, a1, 0, 0, 0);    \
            a2 = __builtin_amdgcn_mfma_f32_16x16x32_f16(afrag[2][KT], bf, a2, 0, 0, 0);    \
            a3 = __builtin_amdgcn_mfma_f32_16x16x32_f16(afrag[3][KT], bf, a3, 0, 0, 0); }
        MSTEP(bq0, 0) MSTEP(bq1, 1) MSTEP(bq2, 2) MSTEP(bq3, 3)
        MSTEP(bq4, 4) MSTEP(bq5, 5) MSTEP(bq6, 6) MSTEP(bq7, 7)
        #undef MSTEP

        f32x4 am = (mt_own == 0) ? a0 : (mt_own == 1) ? a1 : (mt_own == 2) ? a2 : a3;
        float s  = (r_own == 0) ? am[0] : (r_own == 1) ? am[1] : (r_own == 2) ? am[2] : am[3];

        float act = fast_tanh(s + e_cur);
        h_reg = alpha * h_reg + onema * act;
        hlds[CUR ^ 1][m] = (_Float16)h_reg;
        if (write_all)
            *((_Float16*)(bb + (size_t)t * HIDDEN) + m) = (_Float16)h_reg;
        barrier_lds_only();
        e_cur = e_n1;
        e_n1 = e_n2;
    };

    for (int t = t0; t < tend; t += 2) {
        step(std::integral_constant<int, 0>{}, t);
        step(std::integral_constant<int, 1>{}, t + 1);
    }
    h_carry[b * 256 + m] = h_reg;
}

// ---------------- ext GEMM chunk (r17 32-row tiles; bfrag from packed f16; staging trimmed) ----------------
__device__ __forceinline__ void gemm_chunk(
    char* smem, float* buf, const _Float16* __restrict__ Wp,
    const float* __restrict__ bias, int g, int c)
{
    constexpr int KT = 8, ROWB = 512;
    char* alds = smem;   // 32 rows * 512B = 16 KB
    const int tid = threadIdx.x;
    const int wave = tid >> 6, lane = tid & 63;
    const int bl = lane & 15, q = lane >> 4;
    const size_t m0 = (size_t)(g / TBLK) * SEQ + (size_t)c * CHS + (g % TBLK) * 32;

    f16x8 bfrag[4][KT];
    float bv[4];
    #pragma unroll
    for (int nt = 0; nt < 4; ++nt) {
        #pragma unroll
        for (int kt = 0; kt < KT; ++kt)
            bfrag[nt][kt] = __builtin_bit_cast(f16x8,
                *(const uint4*)((const char*)Wp + (size_t)(((wave * 4 + nt) * 8 + kt) * 64 + lane) * 16));
        bv[nt] = bias[wave * 64 + nt * 16 + bl];
    }
    // stage exactly 32 f16 rows (r17's loop over-ran into OOB; trimmed)
    #pragma unroll
    for (int it = 0; it < 4; ++it) {
        int idx = tid + it * 256;
        int row = idx >> 5, chunk = idx & 31;
        uint4 u = *(const uint4*)((const char*)buf + (m0 + row) * 1024 + chunk * 16);
        *(uint4*)(alds + row * ROWB + ((chunk * 16) ^ ((row & 7) << 4))) = u;
    }
    __syncthreads();

    f32x4 acc[2][4];
    #pragma unroll
    for (int mt = 0; mt < 2; ++mt)
        #pragma unroll
        for (int nt = 0; nt < 4; ++nt) acc[mt][nt] = (f32x4){0.f, 0.f, 0.f, 0.f};
    #pragma unroll
    for (int kt = 0; kt < KT; ++kt) {
        int inner = kt * 64 + q * 16;
        f16x8 a0 = __builtin_bit_cast(f16x8,
            *(const uint4*)(alds + (0 * 16 + bl) * ROWB + (inner ^ ((bl & 7) << 4))));
        f16x8 a1 = __builtin_bit_cast(f16x8,
            *(const uint4*)(alds + (1 * 16 + bl) * ROWB + (inner ^ ((bl & 7) << 4))));
        #pragma unroll
        for (int nt = 0; nt < 4; ++nt) {
            acc[0][nt] = __builtin_amdgcn_mfma_f32_16x16x32_f16(a0, bfrag[nt][kt], acc[0][nt], 0, 0, 0);
            acc[1][nt] = __builtin_amdgcn_mfma_f32_16x16x32_f16(a1, bfrag[nt][kt], acc[1][nt], 0, 0, 0);
        }
    }
    #pragma unroll
    for (int mt = 0; mt < 2; ++mt)
        #pragma unroll
        for (int nt = 0; nt < 4; ++nt) {
            int col = wave * 64 + nt * 16 + bl;
            #pragma unroll
            for (int r = 0; r < 4; ++r)
                buf[(m0 + mt * 16 + q * 4 + r) * 256 + col] = acc[mt][nt][r] + bv[nt];
        }
}

// ---------------- stage megakernel (r17 structure) ----------------
// blocks [0,64): scanL0(stage); [64,128): scanL1(stage-2); [128,192): scanL2(stage-4);
// [192,192+128): gemm1(stage-1); next 128: gemm2(stage-3). Deps ride launch order.
__global__ __launch_bounds__(256, 1) void stage_kernel(
    int stage, float* buf,
    const _Float16* __restrict__ wpk,   // [5][65536] packed: Wrec0,Wrec1,Wrec2,Win1,Win2
    const float* __restrict__ bias,  const float* __restrict__ alphas,
    float* __restrict__ h_carry)
{
    __shared__ alignas(16) char smem[16384];
    int blk = blockIdx.x;
    if (blk < 192) {
        int layer = blk >> 6;
        int c = stage - 2 * layer;
        if (c < 0 || c >= CCH) return;
        scan_chunk(smem, buf, wpk + (size_t)layer * 65536, alphas + layer * 64,
                   h_carry + (size_t)layer * 16384, blk & 63, c, layer < 2);
    } else {
        int g = blk - 192;
        int which = g / (64 * TBLK);   // 0: ext1 gemm, 1: ext2 gemm
        int gl = g % (64 * TBLK);
        int c = stage - 1 - 2 * which;
        if (c < 0 || c >= CCH) return;
        gemm_chunk(smem, buf, wpk + (size_t)(3 + which) * 65536, bias + (which + 1) * 256, gl, c);
    }
}

// ---------------- final projection from h_carry[2] ----------------
__global__ __launch_bounds__(256) void outproj_kernel(
    const float* __restrict__ h_carry, const float* __restrict__ ow, const float* __restrict__ ob,
    float* __restrict__ out)
{
    __shared__ float h_l[256];
    __shared__ float p_lds[4][64];
    int b = blockIdx.x;
    int tid = threadIdx.x;
    h_l[tid] = h_carry[b * 256 + tid];
    __syncthreads();
    int o = tid & 63, qq = tid >> 6;
    float s = 0.f;
    const float4* wp = (const float4*)(ow + o * 256 + qq * 64);
    const float4* hp = (const float4*)(h_l + qq * 64);
    #pragma unroll
    for (int m = 0; m < 16; ++m) {
        float4 wv = wp[m]; float4 hv = hp[m];
        s = fmaf(wv.x, hv.x, s); s = fmaf(wv.y, hv.y, s);
        s = fmaf(wv.z, hv.z, s); s = fmaf(wv.w, hv.w, s);
    }
    p_lds[qq][o] = s;
    __syncthreads();
    if (tid < 64)
        out[b * 64 + tid] = p_lds[0][tid] + p_lds[1][tid] + p_lds[2][tid] + p_lds[3][tid] + ob[tid];
}

extern "C" void kernel_launch(void* const* d_in, const int* in_sizes, int n_in,
                              void* d_out, int out_size, void* d_ws, size_t ws_size,
                              hipStream_t stream)
{
    const float* x     = (const float*)d_in[0];
    const float* cw1   = (const float*)d_in[1];
    const float* cb1   = (const float*)d_in[2];
    const float* cw2   = (const float*)d_in[3];
    const float* cb2   = (const float*)d_in[4];
    const float* pw    = (const float*)d_in[5];
    const float* pb    = (const float*)d_in[6];
    const float* W_rec = (const float*)d_in[7];
    const float* W_in  = (const float*)d_in[8];
    const float* bias  = (const float*)d_in[9];
    const float* tau_b = (const float*)d_in[10];
    const float* tmw   = (const float*)d_in[11];
    const float* tmb   = (const float*)d_in[12];
    const float* ow    = (const float*)d_in[13];
    const float* ob    = (const float*)d_in[14];
    float* out = (float*)d_out;

    char* ws = (char*)d_ws;
    float*     alphas  = (float*)ws;                   // 192 f (768 B)
    float*     h_carry = (float*)(ws + 1024);          // [3][64][256] f = 196608 B
    float*     bf      = (float*)(ws + 197632);        // 256 f
    float*     Wf      = (float*)(ws + 198656);        // 256*128 f = 131072 B
    _Float16*  wpk     = (_Float16*)(ws + 329728);     // [5][65536] f16 = 655360 B
    float*     buf     = (float*)(ws + 1048576);       // [64][2048][256] f32 = 134.2MB

    const int MROWS = BATCH * SEQ;      // 131072
    const int NGBLK = 192 + 2 * 64 * TBLK;   // 448 blocks per stage

    prep_kernel<<<64, 1024, 0, stream>>>(x, cw1, cb1, cw2, cb2, tau_b, tmw, tmb, alphas, h_carry);
    wf_kernel<<<256, 128, 0, stream>>>(W_in, pw, pb, bias, Wf, bf);

    // one-time f16 fragment packing: Wrec0/1/2, Win1, Win2
    wpack_kernel<<<128, 64, 0, stream>>>(W_rec,                wpk);
    wpack_kernel<<<128, 64, 0, stream>>>(W_rec + 65536,        wpk + 65536);
    wpack_kernel<<<128, 64, 0, stream>>>(W_rec + 131072,       wpk + 2 * 65536);
    wpack_kernel<<<128, 64, 0, stream>>>(W_in + 65536,         wpk + 3 * 65536);
    wpack_kernel<<<128, 64, 0, stream>>>(W_in + 131072,        wpk + 4 * 65536);

    // ext0 = x @ Wf.T + bf (input projection + W_in0 fused), full sequence
    gemm0_kernel<<<MROWS / 32, 256, 0, stream>>>(x, Wf, bf, buf);

    // speculative chunked pipeline: 3 scans + 2 ext-gemms overlapped across launches
    for (int s = 0; s < CCH + 4; ++s)
        stage_kernel<<<NGBLK, 256, 0, stream>>>(s, buf, wpk, bias, alphas, h_carry);

    outproj_kernel<<<64, 256, 0, stream>>>(h_carry + 2 * 16384, ow, ob, out);
}